// Round 2
// baseline (212.419 us; speedup 1.0000x reference)
//
#include <hip/hip_runtime.h>
#include <hip/hip_bf16.h>

// Problem constants (fixed by the reference generator).
constexpr int E      = 2048;   // edges
constexpr int NVARS  = 512;    // variable nodes
constexpr int MAXP   = 20;     // max fan-in slots (deg-1 <= ~14; 20 = safety, mult of 4)
constexpr int NCH    = 8;      // row chunks for deterministic compaction
constexpr int CHROWS = E / NCH;           // 256 rows per chunk
constexpr int TB     = 4;      // batch rows per block in main kernel
constexpr int NT     = 512;    // threads per block in main kernel

// ---------------------------------------------------------------------------
// Pass A: per-(chunk, column) nonzero counts of the E x E mask.
// thread <-> column, loop over rows => every load coalesced across lanes.
// ---------------------------------------------------------------------------
__global__ __launch_bounds__(256)
void pass_count(const float* __restrict__ mask, int* __restrict__ chunkcnt)
{
    const int col = blockIdx.x * 256 + threadIdx.x;
    const int ch  = blockIdx.y;
    const int r0  = ch * CHROWS;
    int cnt = 0;
    #pragma unroll 8
    for (int r = r0; r < r0 + CHROWS; ++r)
        cnt += (mask[(size_t)r * E + col] != 0.0f);
    chunkcnt[ch * E + col] = cnt;
}

// ---------------------------------------------------------------------------
// Pass B: deterministic row-ordered compaction into packed table
//   tbl[slot][col] = { w = mask*odd_w*dropout_gate , src-row as int bits }
// Base slot for this chunk = prefix sum of earlier chunks' counts.
// ---------------------------------------------------------------------------
__global__ __launch_bounds__(256)
void pass_compact(const float* __restrict__ mask,
                  const float* __restrict__ odd_w,
                  const float* __restrict__ u,
                  const float* __restrict__ logits,
                  const int*   __restrict__ chunkcnt,
                  float2* __restrict__ tbl)
{
    const int col = blockIdx.x * 256 + threadIdx.x;
    const int ch  = blockIdx.y;
    int base = 0;
    for (int c = 0; c < ch; ++c) base += chunkcnt[c * E + col];

    const int r0 = ch * CHROWS;
    for (int r = r0; r < r0 + CHROWS; ++r) {
        const float m = mask[(size_t)r * E + col];
        if (m != 0.0f) {
            if (base < MAXP) {
                const float l   = logits[r];
                const float sig = 1.0f / (1.0f + __expf(-l));
                const float z   = (u[r] < sig) ? 1.0f : 0.0f;
                const float w   = m * odd_w[(size_t)r * E + col] * z;
                tbl[(size_t)base * E + col] = make_float2(w, __int_as_float(r));
            }
            ++base;
        }
    }
}

// ---------------------------------------------------------------------------
// Pass C: round counts up to a multiple of 4 (zero-pad the extra slots) and
// scan the skip mask (one nonzero per column) -> vars_, fused skip weight.
// blockIdx.y selects a 64-row stripe of the [NVARS][E] skip mask.
// ---------------------------------------------------------------------------
__global__ __launch_bounds__(256)
void pass_finish(const int*   __restrict__ chunkcnt,
                 const float* __restrict__ skip_mask,
                 const float* __restrict__ llr_w,
                 float2* __restrict__ tbl,
                 int*    __restrict__ cnt4s,
                 int*    __restrict__ vars_,
                 float*  __restrict__ skw)
{
    const int col = blockIdx.x * 256 + threadIdx.x;

    if (blockIdx.y == 0) {
        int tot = 0;
        #pragma unroll
        for (int c = 0; c < NCH; ++c) tot += chunkcnt[c * E + col];
        if (tot > MAXP) tot = MAXP;
        int c4 = (tot + 3) & ~3;
        if (c4 > MAXP) c4 = MAXP;
        cnt4s[col] = c4;
        for (int j = tot; j < c4; ++j)
            tbl[(size_t)j * E + col] = make_float2(0.0f, __int_as_float(0));
    }

    const int v0 = blockIdx.y * (NVARS / 8);
    for (int v = v0; v < v0 + NVARS / 8; ++v) {
        const float m = skip_mask[(size_t)v * E + col];
        if (m != 0.0f) {               // exactly one stripe finds it: no race
            vars_[col] = v;
            skw [col]  = m * llr_w[(size_t)v * E + col];
        }
    }
}

// tanh(0.5*clip(s,-10,10)) = (e^c - 1)/(e^c + 1)
__device__ __forceinline__ float tanh_half_clip(float s) {
    float c = fminf(fmaxf(s, -10.0f), 10.0f);
    float t = __expf(c);
    return (t - 1.0f) * __frcp_rn(t + 1.0f);
}

// ---------------------------------------------------------------------------
// Main fused kernel: sparse gather + skip + tanh.
// 512 threads, TB=4 rows staged in LDS (40960 B -> 4 blocks/CU = 160 KiB,
// 32 waves/CU). Inner loop unrolled x4 over zero-padded table slots.
// ---------------------------------------------------------------------------
__global__ __launch_bounds__(NT, 8)
void fused_main(const float* __restrict__ x,     // [B, E]
                const float* __restrict__ llr,   // [B, NVARS]
                const float2* __restrict__ tbl,  // [MAXP][E]
                const int*   __restrict__ cnt4s,
                const int*   __restrict__ vars_,
                const float* __restrict__ skw,
                float* __restrict__ out)
{
    __shared__ float xs[TB][E];
    __shared__ float ls[TB][NVARS];

    const int b0 = blockIdx.x * TB;
    const int t  = threadIdx.x;

    // Stage x rows: TB*E/4 = 2048 float4 by 512 threads -> 4 each, coalesced.
    const float4* xg  = (const float4*)(x + (size_t)b0 * E);
    float4*       xsv = (float4*)&xs[0][0];
    #pragma unroll
    for (int i = 0; i < (TB * E / 4) / NT; ++i)
        xsv[i * NT + t] = xg[i * NT + t];

    // Stage llr rows: TB*NVARS/4 = 512 float4 -> 1 each.
    const float4* lg  = (const float4*)(llr + (size_t)b0 * NVARS);
    float4*       lsv = (float4*)&ls[0][0];
    lsv[t] = lg[t];

    __syncthreads();

    #pragma unroll
    for (int k = 0; k < E / NT; ++k) {
        const int e    = k * NT + t;           // consecutive across lanes
        const int c4   = cnt4s[e];
        const int v    = vars_[e];
        const float sv = skw[e];

        float a0 = sv * ls[0][v];
        float a1 = sv * ls[1][v];
        float a2 = sv * ls[2][v];
        float a3 = sv * ls[3][v];

        const float2* tp = tbl + e;
        for (int j = 0; j < c4; j += 4) {
            const float2 p0 = tp[(size_t)(j + 0) * E];
            const float2 p1 = tp[(size_t)(j + 1) * E];
            const float2 p2 = tp[(size_t)(j + 2) * E];
            const float2 p3 = tp[(size_t)(j + 3) * E];
            const int s0 = __float_as_int(p0.y);
            const int s1 = __float_as_int(p1.y);
            const int s2 = __float_as_int(p2.y);
            const int s3 = __float_as_int(p3.y);
            a0 += p0.x * xs[0][s0];
            a1 += p0.x * xs[1][s0];
            a2 += p0.x * xs[2][s0];
            a3 += p0.x * xs[3][s0];
            a0 += p1.x * xs[0][s1];
            a1 += p1.x * xs[1][s1];
            a2 += p1.x * xs[2][s1];
            a3 += p1.x * xs[3][s1];
            a0 += p2.x * xs[0][s2];
            a1 += p2.x * xs[1][s2];
            a2 += p2.x * xs[2][s2];
            a3 += p2.x * xs[3][s2];
            a0 += p3.x * xs[0][s3];
            a1 += p3.x * xs[1][s3];
            a2 += p3.x * xs[2][s3];
            a3 += p3.x * xs[3][s3];
        }

        const size_t o = (size_t)b0 * E + e;
        out[o]         = tanh_half_clip(a0);
        out[o + E]     = tanh_half_clip(a1);
        out[o + 2 * E] = tanh_half_clip(a2);
        out[o + 3 * E] = tanh_half_clip(a3);
    }
}

extern "C" void kernel_launch(void* const* d_in, const int* in_sizes, int n_in,
                              void* d_out, int out_size, void* d_ws, size_t ws_size,
                              hipStream_t stream) {
    const float* x        = (const float*)d_in[0];  // [B, E]
    const float* llr      = (const float*)d_in[1];  // [B, NVARS]
    const float* u        = (const float*)d_in[2];  // [E]
    const float* odd_w    = (const float*)d_in[3];  // [E, E]
    const float* llr_w    = (const float*)d_in[4];  // [NVARS, E]
    const float* logits   = (const float*)d_in[5];  // [E]
    const float* o2e_mask = (const float*)d_in[6];  // [E, E]
    const float* skip_msk = (const float*)d_in[7];  // [NVARS, E]
    float* out = (float*)d_out;

    const int B = in_sizes[0] / E;                  // 16384

    // Workspace layout (~418 KB).
    char* wsb = (char*)d_ws;
    float2* tbl      = (float2*)(wsb);                                   // 327680 B
    int*    chunkcnt = (int*)   (wsb + (size_t)MAXP * E * 8);            //  65536 B
    int*    cnt4s    = (int*)   (wsb + (size_t)MAXP * E * 8 + NCH*E*4);  //   8192 B
    int*    vars_    = (int*)   (wsb + (size_t)MAXP * E * 8 + NCH*E*4 + E*4);
    float*  skw      = (float*) (wsb + (size_t)MAXP * E * 8 + NCH*E*4 + 2*E*4);

    pass_count  <<<dim3(E / 256, NCH), dim3(256), 0, stream>>>(o2e_mask, chunkcnt);
    pass_compact<<<dim3(E / 256, NCH), dim3(256), 0, stream>>>(
        o2e_mask, odd_w, u, logits, chunkcnt, tbl);
    pass_finish <<<dim3(E / 256, 8), dim3(256), 0, stream>>>(
        chunkcnt, skip_msk, llr_w, tbl, cnt4s, vars_, skw);

    fused_main<<<dim3(B / TB), dim3(NT), 0, stream>>>(
        x, llr, tbl, cnt4s, vars_, skw, out);
}

// Round 3
// 161.461 us; speedup vs baseline: 1.3156x; 1.3156x over previous
//
#include <hip/hip_runtime.h>
#include <hip/hip_bf16.h>

constexpr int E     = 2048;   // edges
constexpr int NVARS = 512;    // variable nodes
constexpr int MAXP  = 24;     // table slots per column (max fan-in ~14; mult of 4)
constexpr int NCH   = 32;     // row chunks for deterministic compaction
constexpr int CHR   = E / NCH;            // 64 rows per chunk
constexpr int TB    = 4;      // batch rows per block in main kernel
constexpr int NT    = 512;    // threads per block in main kernel

// ---------------------------------------------------------------------------
// Pass A: per-(chunk, column) nonzero counts (u8). Coalesced; 256 blocks.
// ---------------------------------------------------------------------------
__global__ __launch_bounds__(256)
void pass_count(const float* __restrict__ mask, unsigned char* __restrict__ ccnt)
{
    const int col = blockIdx.x * 256 + threadIdx.x;
    const int r0  = blockIdx.y * CHR;
    int cnt = 0;
    #pragma unroll 8
    for (int r = r0; r < r0 + CHR; ++r)
        cnt += (mask[(size_t)r * E + col] != 0.0f);
    ccnt[blockIdx.y * E + col] = (unsigned char)cnt;
}

// ---------------------------------------------------------------------------
// Pass B: deterministic row-ordered compaction into packed column-contiguous
// table: tbl[col*MAXP + slot] = (bf16(w) << 16) | src_row.
// w = mask * odd_w * dropout_gate, rounded to nearest bf16.
// ---------------------------------------------------------------------------
__global__ __launch_bounds__(256)
void pass_compact(const float* __restrict__ mask,
                  const float* __restrict__ odd_w,
                  const float* __restrict__ u,
                  const float* __restrict__ logits,
                  const unsigned char* __restrict__ ccnt,
                  unsigned int* __restrict__ tbl)
{
    const int col = blockIdx.x * 256 + threadIdx.x;
    const int ch  = blockIdx.y;
    int base = 0;
    for (int c = 0; c < ch; ++c) base += ccnt[c * E + col];

    const int r0 = ch * CHR;
    for (int r = r0; r < r0 + CHR; ++r) {
        const float m = mask[(size_t)r * E + col];
        if (m != 0.0f) {
            if (base < MAXP) {
                const float sig = 1.0f / (1.0f + __expf(-logits[r]));
                const float z   = (u[r] < sig) ? 1.0f : 0.0f;
                const float w   = m * odd_w[(size_t)r * E + col] * z;
                const unsigned wb = (__float_as_uint(w) + 0x8000u) & 0xFFFF0000u;
                tbl[(size_t)col * MAXP + base] = wb | (unsigned)r;
            }
            ++base;
        }
    }
}

// ---------------------------------------------------------------------------
// Pass C: per-column totals -> c4 (mult of 4), zero-pad slots, and scan the
// skip mask (exactly one nonzero per column) -> meta = {skip_w, var}.
// grid (8, 16): y==0 also does totals; each y scans a 32-row stripe.
// ---------------------------------------------------------------------------
__global__ __launch_bounds__(256)
void pass_finish(const unsigned char* __restrict__ ccnt,
                 const float* __restrict__ skip_mask,
                 const float* __restrict__ llr_w,
                 unsigned int* __restrict__ tbl,
                 int*    __restrict__ c4s,
                 float2* __restrict__ meta)
{
    const int col = blockIdx.x * 256 + threadIdx.x;

    if (blockIdx.y == 0) {
        int tot = 0;
        #pragma unroll
        for (int c = 0; c < NCH; ++c) tot += ccnt[c * E + col];
        if (tot > MAXP) tot = MAXP;
        int c4 = (tot + 3) & ~3;
        if (c4 > MAXP) c4 = MAXP;
        c4s[col] = c4;
        for (int j = tot; j < c4; ++j)
            tbl[(size_t)col * MAXP + j] = 0u;   // w=0, src=0 (harmless)
    }

    const int v0 = blockIdx.y * (NVARS / 16);
    for (int v = v0; v < v0 + NVARS / 16; ++v) {
        const float m = skip_mask[(size_t)v * E + col];
        if (m != 0.0f)                           // exactly one stripe finds it
            meta[col] = make_float2(m * llr_w[(size_t)v * E + col],
                                    __int_as_float(v));
    }
}

// tanh(0.5*clip(s,-10,10)) = (e^c - 1)/(e^c + 1)
__device__ __forceinline__ float tanh_half_clip(float s) {
    float c = fminf(fmaxf(s, -10.0f), 10.0f);
    float t = __expf(c);
    return (t - 1.0f) * __frcp_rn(t + 1.0f);
}

// ---------------------------------------------------------------------------
// Main fused kernel. x tile stored as row-pairs (float2) so one ds_read_b64
// serves 2 batch rows (16 bank-pair bins, ~4-way: 1.58x, vs b128's 8-bin
// 2.9x). Table entries packed to 4B, loaded 4-at-a-time via uint4.
// LDS = 2*16KB + 2*4KB = 40KB -> 4 blocks/CU, 32 waves/CU.
// ---------------------------------------------------------------------------
__global__ __launch_bounds__(NT, 8)
void fused_main(const float* __restrict__ x,     // [B, E]
                const float* __restrict__ llr,   // [B, NVARS]
                const unsigned int* __restrict__ tbl,  // [E][MAXP] packed
                const int*   __restrict__ c4s,
                const float2* __restrict__ meta,
                float* __restrict__ out)
{
    __shared__ float2 xsA[E];      // (row b0, row b1)
    __shared__ float2 xsB[E];      // (row b2, row b3)
    __shared__ float2 lsA[NVARS];
    __shared__ float2 lsB[NVARS];

    const int b0 = blockIdx.x * TB;
    const int t  = threadIdx.x;

    const float* xr = x + (size_t)b0 * E;
    #pragma unroll
    for (int i = 0; i < E / NT; ++i) {
        const int e = i * NT + t;                 // consecutive e across lanes
        xsA[e] = make_float2(xr[e],         xr[E + e]);
        xsB[e] = make_float2(xr[2 * E + e], xr[3 * E + e]);
    }
    const float* lr = llr + (size_t)b0 * NVARS;
    {
        const int v = t;                          // NT == NVARS
        lsA[v] = make_float2(lr[v],             lr[NVARS + v]);
        lsB[v] = make_float2(lr[2 * NVARS + v], lr[3 * NVARS + v]);
    }
    __syncthreads();

    #pragma unroll
    for (int k = 0; k < E / NT; ++k) {
        const int e = k * NT + t;
        const float2 mt = meta[e];
        const int   v  = __float_as_int(mt.y);
        const int   c4 = c4s[e];
        const float sk = mt.x;

        const float2 lA = lsA[v], lB = lsB[v];
        float a0 = sk * lA.x, a1 = sk * lA.y, a2 = sk * lB.x, a3 = sk * lB.y;

        const uint4* tc = (const uint4*)(tbl + (size_t)e * MAXP);
        for (int j4 = 0; j4 < c4; j4 += 4) {
            const uint4 g = tc[j4 >> 2];
            {
                const float w = __uint_as_float(g.x & 0xFFFF0000u);
                const int   s = (int)(g.x & 0xFFFFu);
                const float2 pA = xsA[s], pB = xsB[s];
                a0 += w * pA.x; a1 += w * pA.y; a2 += w * pB.x; a3 += w * pB.y;
            }
            {
                const float w = __uint_as_float(g.y & 0xFFFF0000u);
                const int   s = (int)(g.y & 0xFFFFu);
                const float2 pA = xsA[s], pB = xsB[s];
                a0 += w * pA.x; a1 += w * pA.y; a2 += w * pB.x; a3 += w * pB.y;
            }
            {
                const float w = __uint_as_float(g.z & 0xFFFF0000u);
                const int   s = (int)(g.z & 0xFFFFu);
                const float2 pA = xsA[s], pB = xsB[s];
                a0 += w * pA.x; a1 += w * pA.y; a2 += w * pB.x; a3 += w * pB.y;
            }
            {
                const float w = __uint_as_float(g.w & 0xFFFF0000u);
                const int   s = (int)(g.w & 0xFFFFu);
                const float2 pA = xsA[s], pB = xsB[s];
                a0 += w * pA.x; a1 += w * pA.y; a2 += w * pB.x; a3 += w * pB.y;
            }
        }

        const size_t o = (size_t)b0 * E + e;
        out[o]         = tanh_half_clip(a0);
        out[o + E]     = tanh_half_clip(a1);
        out[o + 2 * E] = tanh_half_clip(a2);
        out[o + 3 * E] = tanh_half_clip(a3);
    }
}

extern "C" void kernel_launch(void* const* d_in, const int* in_sizes, int n_in,
                              void* d_out, int out_size, void* d_ws, size_t ws_size,
                              hipStream_t stream) {
    const float* x        = (const float*)d_in[0];  // [B, E]
    const float* llr      = (const float*)d_in[1];  // [B, NVARS]
    const float* u        = (const float*)d_in[2];  // [E]
    const float* odd_w    = (const float*)d_in[3];  // [E, E]
    const float* llr_w    = (const float*)d_in[4];  // [NVARS, E]
    const float* logits   = (const float*)d_in[5];  // [E]
    const float* o2e_mask = (const float*)d_in[6];  // [E, E]
    const float* skip_msk = (const float*)d_in[7];  // [NVARS, E]
    float* out = (float*)d_out;

    const int B = in_sizes[0] / E;                  // 16384

    // Workspace layout (~287 KB, all 16B-aligned).
    char* wsb = (char*)d_ws;
    unsigned int* tbl  = (unsigned int*)(wsb);                       // 196608 B
    float2*       meta = (float2*)(wsb + (size_t)E * MAXP * 4);      //  16384 B
    int*          c4s  = (int*)   (wsb + (size_t)E * MAXP * 4 + E * 8);       // 8192 B
    unsigned char* ccnt= (unsigned char*)(wsb + (size_t)E * MAXP * 4 + E * 12); // 65536 B

    pass_count  <<<dim3(E / 256, NCH), dim3(256), 0, stream>>>(o2e_mask, ccnt);
    pass_compact<<<dim3(E / 256, NCH), dim3(256), 0, stream>>>(
        o2e_mask, odd_w, u, logits, ccnt, tbl);
    pass_finish <<<dim3(E / 256, 16), dim3(256), 0, stream>>>(
        ccnt, skip_msk, llr_w, tbl, c4s, meta);

    fused_main<<<dim3(B / TB), dim3(NT), 0, stream>>>(
        x, llr, tbl, c4s, meta, out);
}

// Round 4
// 136.596 us; speedup vs baseline: 1.5551x; 1.1820x over previous
//
#include <hip/hip_runtime.h>
#include <hip/hip_bf16.h>

constexpr int E     = 2048;   // edges
constexpr int NVARS = 512;    // variable nodes
constexpr int MAXP  = 24;     // table slots per column (max fan-in ~14)
constexpr int NBLK  = MAXP / 4;           // 4-entry blocks per column
constexpr int NCH   = 32;     // row chunks for deterministic compaction
constexpr int CHR   = E / NCH;            // 64 rows per chunk
constexpr int TB    = 8;      // batch rows per block in main kernel
constexpr int NT    = 512;    // threads per block in main kernel

// ---------------------------------------------------------------------------
// Pass A: per-(chunk, column) nonzero counts (u8). Coalesced; 256 blocks.
// ---------------------------------------------------------------------------
__global__ __launch_bounds__(256)
void pass_count(const float* __restrict__ mask, unsigned char* __restrict__ ccnt)
{
    const int col = blockIdx.x * 256 + threadIdx.x;
    const int r0  = blockIdx.y * CHR;
    int cnt = 0;
    #pragma unroll 8
    for (int r = r0; r < r0 + CHR; ++r)
        cnt += (mask[(size_t)r * E + col] != 0.0f);
    ccnt[blockIdx.y * E + col] = (unsigned char)cnt;
}

// ---------------------------------------------------------------------------
// Pass B: deterministic row-ordered compaction into slot-block-major table:
//   u32 entry = (bf16(w) << 16) | src_row, at tbl[((slot/4)*E + col)*4 + slot%4]
// so a uint4 at (blk*E + col)*16B holds 4 consecutive slots of column col,
// and lane-consecutive col => fully coalesced uint4 loads in the main kernel.
// Table is pre-zeroed (memset) so pad slots / guard block read as w=0.
// ---------------------------------------------------------------------------
__global__ __launch_bounds__(256)
void pass_compact(const float* __restrict__ mask,
                  const float* __restrict__ odd_w,
                  const float* __restrict__ u,
                  const float* __restrict__ logits,
                  const unsigned char* __restrict__ ccnt,
                  unsigned int* __restrict__ tbl)
{
    const int col = blockIdx.x * 256 + threadIdx.x;
    const int ch  = blockIdx.y;
    int base = 0;
    for (int c = 0; c < ch; ++c) base += ccnt[c * E + col];

    const int r0 = ch * CHR;
    for (int r = r0; r < r0 + CHR; ++r) {
        const float m = mask[(size_t)r * E + col];
        if (m != 0.0f) {
            if (base < MAXP) {
                const float sig = 1.0f / (1.0f + __expf(-logits[r]));
                const float z   = (u[r] < sig) ? 1.0f : 0.0f;
                const float w   = m * odd_w[(size_t)r * E + col] * z;
                const unsigned wb = (__float_as_uint(w) + 0x8000u) & 0xFFFF0000u;
                tbl[((size_t)(base >> 2) * E + col) * 4 + (base & 3)] = wb | (unsigned)r;
            }
            ++base;
        }
    }
}

// ---------------------------------------------------------------------------
// Pass C: skip-mask scan (exactly one nonzero per column). The finding thread
// also totals the fan-in and writes packed meta = {skw, v | (nblk<<16)}.
// grid (8, 16): each y scans a 32-row stripe; single writer per column.
// ---------------------------------------------------------------------------
__global__ __launch_bounds__(256)
void pass_meta(const unsigned char* __restrict__ ccnt,
               const float* __restrict__ skip_mask,
               const float* __restrict__ llr_w,
               float2* __restrict__ meta)
{
    const int col = blockIdx.x * 256 + threadIdx.x;
    const int v0  = blockIdx.y * (NVARS / 16);
    for (int v = v0; v < v0 + NVARS / 16; ++v) {
        const float m = skip_mask[(size_t)v * E + col];
        if (m != 0.0f) {                       // exactly one stripe finds it
            int tot = 0;
            #pragma unroll
            for (int c = 0; c < NCH; ++c) tot += ccnt[c * E + col];
            if (tot > MAXP) tot = MAXP;
            const int nblk = (tot + 3) >> 2;   // 4-entry blocks to process
            meta[col] = make_float2(m * llr_w[(size_t)v * E + col],
                                    __int_as_float(v | (nblk << 16)));
        }
    }
}

// RNE float -> bf16 bits (low 16).
__device__ __forceinline__ unsigned bf16r(float f) {
    const unsigned uu = __float_as_uint(f);
    return (uu + 0x7FFFu + ((uu >> 16) & 1u)) >> 16;
}
__device__ __forceinline__ unsigned pk2(float a, float b) {
    return bf16r(a) | (bf16r(b) << 16);
}
// unpack: low half / high half of a packed pair
__device__ __forceinline__ float bl(unsigned q) { return __uint_as_float(q << 16); }
__device__ __forceinline__ float bh(unsigned q) { return __uint_as_float(q & 0xFFFF0000u); }

// tanh(0.5*clip(s,-10,10)) = (e^c - 1)/(e^c + 1)
__device__ __forceinline__ float tanh_half_clip(float s) {
    float c = fminf(fmaxf(s, -10.0f), 10.0f);
    float t = __expf(c);
    return (t - 1.0f) * __frcp_rn(t + 1.0f);
}

// ---------------------------------------------------------------------------
// Main fused kernel. TB=8 batch rows; x staged in LDS as bf16, 4 rows per
// uint2 word-pair => ONE ds_read_b64 serves 4 rows (xsLo: rows 0-3,
// xsHi: rows 4-7). llr staged f32 as float4 per 4 rows. Table read as
// coalesced uint4 (4 entries) with register double-buffer prefetch.
// LDS = 16+16+8+8 = 48 KB -> 3 blocks/CU, 24 waves/CU.
// ---------------------------------------------------------------------------
__global__ __launch_bounds__(NT, 6)
void fused_main(const float* __restrict__ x,     // [B, E]
                const float* __restrict__ llr,   // [B, NVARS]
                const unsigned int* __restrict__ tbl,  // [NBLK+1][E] uint4 blocks
                const float2* __restrict__ meta,
                float* __restrict__ out)
{
    __shared__ uint2  xsLo[E];     // rows b0..b3, bf16 packed
    __shared__ uint2  xsHi[E];     // rows b4..b7
    __shared__ float4 lsLo[NVARS]; // llr rows b0..b3 (f32)
    __shared__ float4 lsHi[NVARS]; // llr rows b4..b7

    const int b0 = blockIdx.x * TB;
    const int t  = threadIdx.x;

    const float* xr = x + (size_t)b0 * E;
    #pragma unroll
    for (int i = 0; i < E / NT; ++i) {
        const int e = i * NT + t;                 // consecutive across lanes
        uint2 lo, hi;
        lo.x = pk2(xr[e],         xr[E + e]);
        lo.y = pk2(xr[2 * E + e], xr[3 * E + e]);
        hi.x = pk2(xr[4 * E + e], xr[5 * E + e]);
        hi.y = pk2(xr[6 * E + e], xr[7 * E + e]);
        xsLo[e] = lo;
        xsHi[e] = hi;
    }
    const float* lr = llr + (size_t)b0 * NVARS;
    {
        const int v = t;                          // NT == NVARS
        lsLo[v] = make_float4(lr[v], lr[NVARS + v], lr[2 * NVARS + v], lr[3 * NVARS + v]);
        lsHi[v] = make_float4(lr[4 * NVARS + v], lr[5 * NVARS + v],
                              lr[6 * NVARS + v], lr[7 * NVARS + v]);
    }
    __syncthreads();

    #pragma unroll
    for (int k = 0; k < E / NT; ++k) {
        const int e = k * NT + t;
        const float2 mt = meta[e];
        const int vc = __float_as_int(mt.y);
        const int v  = vc & 0xFFFF;
        const int nb = vc >> 16;                  // number of uint4 blocks
        const float sk = mt.x;

        const float4 llo = lsLo[v], lhi = lsHi[v];
        float a0 = sk * llo.x, a1 = sk * llo.y, a2 = sk * llo.z, a3 = sk * llo.w;
        float a4 = sk * lhi.x, a5 = sk * lhi.y, a6 = sk * lhi.z, a7 = sk * lhi.w;

        const uint4* tq = (const uint4*)tbl + e;  // tq[blk*E] = 4 slots of col e
        uint4 g = tq[0];                          // always valid (zeroed table)
        for (int ib = 0; ib < nb; ++ib) {
            const uint4 gn = tq[(size_t)(ib + 1) * E];  // guard block at NBLK
            #pragma unroll
            for (int q = 0; q < 4; ++q) {
                const unsigned ent = (q == 0) ? g.x : (q == 1) ? g.y : (q == 2) ? g.z : g.w;
                const float wv = __uint_as_float(ent & 0xFFFF0000u);
                const int   s  = (int)(ent & 0x7FFu);
                const uint2 lo = xsLo[s];
                const uint2 hi = xsHi[s];
                a0 += wv * bl(lo.x); a1 += wv * bh(lo.x);
                a2 += wv * bl(lo.y); a3 += wv * bh(lo.y);
                a4 += wv * bl(hi.x); a5 += wv * bh(hi.x);
                a6 += wv * bl(hi.y); a7 += wv * bh(hi.y);
            }
            g = gn;
        }

        const size_t o = (size_t)b0 * E + e;
        out[o]         = tanh_half_clip(a0);
        out[o + E]     = tanh_half_clip(a1);
        out[o + 2 * E] = tanh_half_clip(a2);
        out[o + 3 * E] = tanh_half_clip(a3);
        out[o + 4 * E] = tanh_half_clip(a4);
        out[o + 5 * E] = tanh_half_clip(a5);
        out[o + 6 * E] = tanh_half_clip(a6);
        out[o + 7 * E] = tanh_half_clip(a7);
    }
}

extern "C" void kernel_launch(void* const* d_in, const int* in_sizes, int n_in,
                              void* d_out, int out_size, void* d_ws, size_t ws_size,
                              hipStream_t stream) {
    const float* x        = (const float*)d_in[0];  // [B, E]
    const float* llr      = (const float*)d_in[1];  // [B, NVARS]
    const float* u        = (const float*)d_in[2];  // [E]
    const float* odd_w    = (const float*)d_in[3];  // [E, E]
    const float* llr_w    = (const float*)d_in[4];  // [NVARS, E]
    const float* logits   = (const float*)d_in[5];  // [E]
    const float* o2e_mask = (const float*)d_in[6];  // [E, E]
    const float* skip_msk = (const float*)d_in[7];  // [NVARS, E]
    float* out = (float*)d_out;

    const int B = in_sizes[0] / E;                  // 16384

    // Workspace: tbl (NBLK+1 uint4-blocks x E, incl. guard) | meta | ccnt.
    const size_t tbl_bytes = (size_t)(NBLK + 1) * E * 16;   // 229376
    char* wsb = (char*)d_ws;
    unsigned int*  tbl  = (unsigned int*)(wsb);
    float2*        meta = (float2*)(wsb + tbl_bytes);                 // 16384 B
    unsigned char* ccnt = (unsigned char*)(wsb + tbl_bytes + E * 8);  // 65536 B

    hipMemsetAsync(tbl, 0, tbl_bytes, stream);

    pass_count  <<<dim3(E / 256, NCH), dim3(256), 0, stream>>>(o2e_mask, ccnt);
    pass_compact<<<dim3(E / 256, NCH), dim3(256), 0, stream>>>(
        o2e_mask, odd_w, u, logits, ccnt, tbl);
    pass_meta   <<<dim3(E / 256, 16), dim3(256), 0, stream>>>(
        ccnt, skip_msk, llr_w, meta);

    fused_main<<<dim3(B / TB), dim3(NT), 0, stream>>>(x, llr, tbl, meta, out);
}